// Round 5
// baseline (580.927 us; speedup 1.0000x reference)
//
#include <hip/hip_runtime.h>
#include <hip/hip_bf16.h>

#define NB 8
#define NN 2048
#define ND 256
#define SCALE 0.1767766952966369f   // 1/sqrt(32)

typedef __attribute__((ext_vector_type(8))) short short8;
typedef __attribute__((ext_vector_type(4))) float f32x4;
typedef unsigned short ushort_t;

static __device__ __forceinline__ ushort_t f2b(float f) {
    union { float f; unsigned int u; } v; v.f = f;
    unsigned int r = (v.u + 0x7FFFu + ((v.u >> 16) & 1u)) >> 16;  // RNE
    return (ushort_t)r;
}

static __device__ __forceinline__ float sigmoidf_(float x) {
    return 1.0f / (1.0f + __expf(-x));
}

// ---------------- K1: deg = rowsum(rel); xg = bf16(x * sigmoid(deg*Wd + bd)) ----------------
__global__ __launch_bounds__(256) void deggate_kernel(const float* __restrict__ rel,
                                                      const float* __restrict__ x,
                                                      const float* __restrict__ Wd,
                                                      const float* __restrict__ bd,
                                                      ushort_t* __restrict__ xg) {
    const int row = blockIdx.x;                    // 0 .. NB*NN-1
    const int t = threadIdx.x;
    const float4* r4 = reinterpret_cast<const float4*>(rel + (size_t)row * NN);
    float4 a = r4[t * 2];
    float4 b = r4[t * 2 + 1];
    float s = a.x + a.y + a.z + a.w + b.x + b.y + b.z + b.w;
    for (int off = 1; off < 64; off <<= 1) s += __shfl_xor(s, off, 64);
    __shared__ float ws[4];
    if ((t & 63) == 0) ws[t >> 6] = s;
    __syncthreads();
    const float dg = ws[0] + ws[1] + ws[2] + ws[3];
    const float xv = x[(size_t)row * ND + t];
    xg[(size_t)row * ND + t] = f2b(xv * sigmoidf_(dg * Wd[t] + bd[t]));
}

// ---------------- K1c: W_qkv f32 -> bf16 ----------------
__global__ __launch_bounds__(256) void wconv_kernel(const float* __restrict__ W,
                                                    ushort_t* __restrict__ Wb) {
    const int idx = (blockIdx.x * 256 + threadIdx.x) * 4;
    float4 wv = *reinterpret_cast<const float4*>(W + idx);
    ushort4 o;
    o.x = f2b(wv.x); o.y = f2b(wv.y); o.z = f2b(wv.z); o.w = f2b(wv.w);
    *reinterpret_cast<ushort4*>(Wb + idx) = o;
}

// ---------------- K2: qkv = Xg @ W^T + b; split/transform outputs ----------------
__global__ __launch_bounds__(256) void qkv_kernel(const ushort_t* __restrict__ xg,
                                                  const ushort_t* __restrict__ Wb,
                                                  const float* __restrict__ bqkv,
                                                  ushort_t* __restrict__ qk,
                                                  ushort_t* __restrict__ vT,
                                                  float* __restrict__ res) {
    __shared__ __align__(16) ushort_t T[64][72];       // e_loc x n_loc transpose tile (9 KB)
    const int t = threadIdx.x;
    const int w = t >> 6;
    const int l = t & 63;
    const int lr = l & 15;
    const int lg = l >> 4;
    const int n0 = blockIdx.x * 64 + w * 16;
    const int c0 = blockIdx.y * 64;

    f32x4 acc[4];
#pragma unroll
    for (int i = 0; i < 4; ++i) acc[i] = (f32x4){0.f, 0.f, 0.f, 0.f};

#pragma unroll
    for (int kb = 0; kb < 8; ++kb) {
        short8 a = *reinterpret_cast<const short8*>(xg + (size_t)(n0 + lr) * ND + kb * 32 + lg * 8);
#pragma unroll
        for (int ct = 0; ct < 4; ++ct) {
            short8 bb = *reinterpret_cast<const short8*>(Wb + (size_t)(c0 + ct * 16 + lr) * ND + kb * 32 + lg * 8);
            acc[ct] = __builtin_amdgcn_mfma_f32_16x16x32_bf16(a, bb, acc[ct], 0, 0, 0);
        }
    }

    if (blockIdx.y < 4) {
#pragma unroll
        for (int ct = 0; ct < 4; ++ct) {
            const int e = c0 + ct * 16 + lr;
            const float bias = bqkv[e];
#pragma unroll
            for (int r = 0; r < 4; ++r) {
                const int n = n0 + lg * 4 + r;
                qk[(size_t)n * ND + e] = f2b(sigmoidf_(acc[ct][r] + bias));
            }
        }
    } else if (blockIdx.y < 8) {
        // value -> vT[b][d][n], transposed through LDS for coalesced writes
#pragma unroll
        for (int ct = 0; ct < 4; ++ct) {
            const int e = c0 + ct * 16 + lr;
            const float bias = bqkv[e];
#pragma unroll
            for (int r = 0; r < 4; ++r)
                T[ct * 16 + lr][w * 16 + lg * 4 + r] = f2b(acc[ct][r] + bias);
        }
        __syncthreads();
        const int e_loc = t >> 2;
        const int nl = (t & 3) * 16;
        const int d = c0 - 256 + e_loc;
        const int ng = blockIdx.x * 64;
        const int b = ng >> 11;
        size_t base = ((size_t)b * ND + d) * NN + (ng & 2047) + nl;
        *reinterpret_cast<short8*>(vT + base)     = *reinterpret_cast<const short8*>(&T[e_loc][nl]);
        *reinterpret_cast<short8*>(vT + base + 8) = *reinterpret_cast<const short8*>(&T[e_loc][nl + 8]);
    } else {
#pragma unroll
        for (int ct = 0; ct < 4; ++ct) {
            const int e = c0 + ct * 16 + lr;
            const float bias = bqkv[e];
#pragma unroll
            for (int r = 0; r < 4; ++r) {
                const int n = n0 + lg * 4 + r;
                res[(size_t)n * ND + (e - 512)] = acc[ct][r] + bias;
            }
        }
    }
}

// ---------------- K3: streaming normalized attention ----------------
// grid (NN/16, NB), block 512 (8 waves). Per iter (m-tile = 256):
//   QK: wave w computes S[16q][32m] for m-slice w -> LDS (double-buffered)
//   PV: wave w computes numer[16q][32d-slice d=w*32..] over all 256 m
// rel_pos slice for iter mt+1 is register-prefetched during iter mt.
__global__ __launch_bounds__(512, 6) void attn_kernel(const ushort_t* __restrict__ qk,
                                                      const ushort_t* __restrict__ vT,
                                                      const float* __restrict__ rel,
                                                      const float* __restrict__ res,
                                                      float* __restrict__ out) {
    __shared__ __align__(16) ushort_t slds[2][16][264];   // 528B row stride: 2-way bank alias (free)
    __shared__ float dsums[8][16];
    const int t = threadIdx.x;
    const int w = t >> 6;        // 0..7
    const int l = t & 63;
    const int lr = l & 15;
    const int lg = l >> 4;
    const int b = blockIdx.y;
    const int q0 = blockIdx.x * 16;

    const ushort_t* qkb = qk + (size_t)b * NN * ND;
    const ushort_t* vTb = vT + (size_t)b * ND * NN;
    const float* relb = rel + (size_t)b * NN * NN;

    // hoist Q fragments (A-layout: row = lane&15, k = (lane>>4)*8 + j)
    short8 aq[8];
#pragma unroll
    for (int kb = 0; kb < 8; ++kb)
        aq[kb] = *reinterpret_cast<const short8*>(qkb + (size_t)(q0 + lr) * ND + kb * 32 + lg * 8);

    f32x4 acc0 = (f32x4){0.f, 0.f, 0.f, 0.f};
    f32x4 acc1 = (f32x4){0.f, 0.f, 0.f, 0.f};
    float dsum[4] = {0.f, 0.f, 0.f, 0.f};

    // prefetch rel slice for mt=0
    float rpa[4], rpb[4];
#pragma unroll
    for (int r = 0; r < 4; ++r) {
        const size_t rb = (size_t)(q0 + lg * 4 + r) * NN + w * 32;
        rpa[r] = relb[rb + lr];
        rpb[r] = relb[rb + 16 + lr];
    }

#pragma unroll 2
    for (int mt = 0; mt < 8; ++mt) {
        const int m0 = mt * 256;
        const int mwv = m0 + w * 32;
        const int buf = mt & 1;

        float rp0[4], rp1[4];
#pragma unroll
        for (int r = 0; r < 4; ++r) { rp0[r] = rpa[r]; rp1[r] = rpb[r]; }
        if (mt < 7) {   // prefetch next iter's rel slice (hides HBM latency under this iter)
            const int mn = (mt + 1) * 256 + w * 32;
#pragma unroll
            for (int r = 0; r < 4; ++r) {
                const size_t rb = (size_t)(q0 + lg * 4 + r) * NN + mn;
                rpa[r] = relb[rb + lr];
                rpb[r] = relb[rb + 16 + lr];
            }
        }

        // S[16q][32m] = Q . K^T over K=256
        f32x4 s0 = (f32x4){0.f, 0.f, 0.f, 0.f};
        f32x4 s1 = (f32x4){0.f, 0.f, 0.f, 0.f};
#pragma unroll
        for (int kb = 0; kb < 8; ++kb) {
            short8 b0 = *reinterpret_cast<const short8*>(qkb + (size_t)(mwv + lr) * ND + kb * 32 + lg * 8);
            short8 b1 = *reinterpret_cast<const short8*>(qkb + (size_t)(mwv + 16 + lr) * ND + kb * 32 + lg * 8);
            s0 = __builtin_amdgcn_mfma_f32_16x16x32_bf16(aq[kb], b0, s0, 0, 0, 0);
            s1 = __builtin_amdgcn_mfma_f32_16x16x32_bf16(aq[kb], b1, s1, 0, 0, 0);
        }

        // scale * rel_pos, denom accumulate, stage S (bf16) to LDS
#pragma unroll
        for (int r = 0; r < 4; ++r) {
            float v0 = s0[r] * SCALE * rp0[r];
            float v1 = s1[r] * SCALE * rp1[r];
            dsum[r] += v0 + v1;
            slds[buf][lg * 4 + r][w * 32 + lr] = f2b(v0);
            slds[buf][lg * 4 + r][w * 32 + 16 + lr] = f2b(v1);
        }
        __syncthreads();

        // PV: numer[16q][32d-slice] += S(16x256) . V(256m x 32d)
#pragma unroll
        for (int kt = 0; kt < 8; ++kt) {
            short8 pa = *reinterpret_cast<const short8*>(&slds[buf][lr][kt * 32 + lg * 8]);
            short8 bv0 = *reinterpret_cast<const short8*>(
                vTb + (size_t)(w * 32 + lr) * NN + m0 + kt * 32 + lg * 8);
            short8 bv1 = *reinterpret_cast<const short8*>(
                vTb + (size_t)(w * 32 + 16 + lr) * NN + m0 + kt * 32 + lg * 8);
            acc0 = __builtin_amdgcn_mfma_f32_16x16x32_bf16(pa, bv0, acc0, 0, 0, 0);
            acc1 = __builtin_amdgcn_mfma_f32_16x16x32_bf16(pa, bv1, acc1, 0, 0, 0);
        }
    }

    // denom: reduce over the 16 lanes of each group, then across the 8 waves
#pragma unroll
    for (int r = 0; r < 4; ++r) {
        float v = dsum[r];
        v += __shfl_xor(v, 1, 64);
        v += __shfl_xor(v, 2, 64);
        v += __shfl_xor(v, 4, 64);
        v += __shfl_xor(v, 8, 64);
        dsum[r] = v;
    }
    __syncthreads();   // all slds reads done before dsums reuse of LDS timeline
    if (lr == 0) {
#pragma unroll
        for (int r = 0; r < 4; ++r) dsums[w][lg * 4 + r] = dsum[r];
    }
    __syncthreads();
    float inv[4];
#pragma unroll
    for (int r = 0; r < 4; ++r) {
        const int q = lg * 4 + r;
        float tot = 0.f;
#pragma unroll
        for (int ww = 0; ww < 8; ++ww) tot += dsums[ww][q];
        inv[r] = 1.0f / (tot + 1e-6f);
    }

#pragma unroll
    for (int r = 0; r < 4; ++r) {
        const size_t o = ((size_t)b * NN + q0 + lg * 4 + r) * ND + w * 32 + lr;
        float v0 = acc0[r] * inv[r] + res[o];
        float v1 = acc1[r] * inv[r] + res[o + 16];
        out[o] = fmaxf(v0, 0.f);
        out[o + 16] = fmaxf(v1, 0.f);
    }
}

extern "C" void kernel_launch(void* const* d_in, const int* in_sizes, int n_in,
                              void* d_out, int out_size, void* d_ws, size_t ws_size,
                              hipStream_t stream) {
    const float* x    = (const float*)d_in[0];
    const float* rel  = (const float*)d_in[1];
    const float* Wqkv = (const float*)d_in[2];
    const float* bqkv = (const float*)d_in[3];
    const float* Wd   = (const float*)d_in[4];
    const float* bd   = (const float*)d_in[5];
    float* out = (float*)d_out;

    char* ws = (char*)d_ws;
    ushort_t* Wb  = (ushort_t*)(ws + 0);               // 384 KB
    ushort_t* xg  = (ushort_t*)(ws + 0x80000);         //   8 MB
    ushort_t* qkb = (ushort_t*)(ws + 0x880000);        //   8 MB
    ushort_t* vT  = (ushort_t*)(ws + 0x1080000);       //   8 MB
    float*    res = (float*)(ws + 0x1880000);          //  16 MB

    deggate_kernel<<<NB * NN, 256, 0, stream>>>(rel, x, Wd, bd, xg);
    wconv_kernel<<<(3 * ND * ND) / 1024, 256, 0, stream>>>(Wqkv, Wb);
    qkv_kernel<<<dim3(NB * NN / 64, 12), 256, 0, stream>>>(xg, Wb, bqkv, qkb, vT, res);
    attn_kernel<<<dim3(NN / 16, NB), 512, 0, stream>>>(qkb, vT, rel, res, out);
}

// Round 9
// 504.008 us; speedup vs baseline: 1.1526x; 1.1526x over previous
//
#include <hip/hip_runtime.h>
#include <hip/hip_bf16.h>

#define NB 8
#define NN 2048
#define ND 256
#define SCALE 0.1767766952966369f   // 1/sqrt(32)

typedef __attribute__((ext_vector_type(8))) short short8;
typedef __attribute__((ext_vector_type(4))) float f32x4;
typedef unsigned short ushort_t;

static __device__ __forceinline__ ushort_t f2b(float f) {
    union { float f; unsigned int u; } v; v.f = f;
    unsigned int r = (v.u + 0x7FFFu + ((v.u >> 16) & 1u)) >> 16;  // RNE
    return (ushort_t)r;
}

static __device__ __forceinline__ float sigmoidf_(float x) {
    return 1.0f / (1.0f + __expf(-x));
}

// ---------------- K1: deg = rowsum(rel); xg = bf16(x * sigmoid(deg*Wd + bd)) ----------------
__global__ __launch_bounds__(256) void deggate_kernel(const float* __restrict__ rel,
                                                      const float* __restrict__ x,
                                                      const float* __restrict__ Wd,
                                                      const float* __restrict__ bd,
                                                      ushort_t* __restrict__ xg) {
    const int row = blockIdx.x;                    // 0 .. NB*NN-1
    const int t = threadIdx.x;
    const float4* r4 = reinterpret_cast<const float4*>(rel + (size_t)row * NN);
    float4 a = r4[t * 2];
    float4 b = r4[t * 2 + 1];
    float s = a.x + a.y + a.z + a.w + b.x + b.y + b.z + b.w;
    for (int off = 1; off < 64; off <<= 1) s += __shfl_xor(s, off, 64);
    __shared__ float ws[4];
    if ((t & 63) == 0) ws[t >> 6] = s;
    __syncthreads();
    const float dg = ws[0] + ws[1] + ws[2] + ws[3];
    const float xv = x[(size_t)row * ND + t];
    xg[(size_t)row * ND + t] = f2b(xv * sigmoidf_(dg * Wd[t] + bd[t]));
}

// ---------------- K1c: W_qkv f32 -> bf16 ----------------
__global__ __launch_bounds__(256) void wconv_kernel(const float* __restrict__ W,
                                                    ushort_t* __restrict__ Wb) {
    const int idx = (blockIdx.x * 256 + threadIdx.x) * 4;
    float4 wv = *reinterpret_cast<const float4*>(W + idx);
    ushort4 o;
    o.x = f2b(wv.x); o.y = f2b(wv.y); o.z = f2b(wv.z); o.w = f2b(wv.w);
    *reinterpret_cast<ushort4*>(Wb + idx) = o;
}

// ---------------- K2: qkv = Xg @ W^T + b; split/transform outputs ----------------
__global__ __launch_bounds__(256) void qkv_kernel(const ushort_t* __restrict__ xg,
                                                  const ushort_t* __restrict__ Wb,
                                                  const float* __restrict__ bqkv,
                                                  ushort_t* __restrict__ qk,
                                                  ushort_t* __restrict__ vT,
                                                  float* __restrict__ res) {
    __shared__ __align__(16) ushort_t T[64][72];       // e_loc x n_loc transpose tile (9 KB)
    const int t = threadIdx.x;
    const int w = t >> 6;
    const int l = t & 63;
    const int lr = l & 15;
    const int lg = l >> 4;
    const int n0 = blockIdx.x * 64 + w * 16;
    const int c0 = blockIdx.y * 64;

    f32x4 acc[4];
#pragma unroll
    for (int i = 0; i < 4; ++i) acc[i] = (f32x4){0.f, 0.f, 0.f, 0.f};

#pragma unroll
    for (int kb = 0; kb < 8; ++kb) {
        short8 a = *reinterpret_cast<const short8*>(xg + (size_t)(n0 + lr) * ND + kb * 32 + lg * 8);
#pragma unroll
        for (int ct = 0; ct < 4; ++ct) {
            short8 bb = *reinterpret_cast<const short8*>(Wb + (size_t)(c0 + ct * 16 + lr) * ND + kb * 32 + lg * 8);
            acc[ct] = __builtin_amdgcn_mfma_f32_16x16x32_bf16(a, bb, acc[ct], 0, 0, 0);
        }
    }

    if (blockIdx.y < 4) {
#pragma unroll
        for (int ct = 0; ct < 4; ++ct) {
            const int e = c0 + ct * 16 + lr;
            const float bias = bqkv[e];
#pragma unroll
            for (int r = 0; r < 4; ++r) {
                const int n = n0 + lg * 4 + r;
                qk[(size_t)n * ND + e] = f2b(sigmoidf_(acc[ct][r] + bias));
            }
        }
    } else if (blockIdx.y < 8) {
        // value -> vT[b][d][n], transposed through LDS for coalesced writes
#pragma unroll
        for (int ct = 0; ct < 4; ++ct) {
            const int e = c0 + ct * 16 + lr;
            const float bias = bqkv[e];
#pragma unroll
            for (int r = 0; r < 4; ++r)
                T[ct * 16 + lr][w * 16 + lg * 4 + r] = f2b(acc[ct][r] + bias);
        }
        __syncthreads();
        const int e_loc = t >> 2;
        const int nl = (t & 3) * 16;
        const int d = c0 - 256 + e_loc;
        const int ng = blockIdx.x * 64;
        const int b = ng >> 11;
        size_t base = ((size_t)b * ND + d) * NN + (ng & 2047) + nl;
        *reinterpret_cast<short8*>(vT + base)     = *reinterpret_cast<const short8*>(&T[e_loc][nl]);
        *reinterpret_cast<short8*>(vT + base + 8) = *reinterpret_cast<const short8*>(&T[e_loc][nl + 8]);
    } else {
#pragma unroll
        for (int ct = 0; ct < 4; ++ct) {
            const int e = c0 + ct * 16 + lr;
            const float bias = bqkv[e];
#pragma unroll
            for (int r = 0; r < 4; ++r) {
                const int n = n0 + lg * 4 + r;
                res[(size_t)n * ND + (e - 512)] = acc[ct][r] + bias;
            }
        }
    }
}

// ---------------- K3: streaming normalized attention ----------------
// grid (NN/16, NB), block 512 (8 waves). Per iter (m-tile = 256):
//   QK: wave w computes S[16q][32m] for m-slice w -> LDS (double-buffered)
//   PV: wave w computes numer[16q][32d-slice d=w*32..] over all 256 m
// rel_pos slice for iter mt+1 is register-prefetched during iter mt.
// __launch_bounds__(512, 4): VGPR cap 128 (live state ~110; (512,6)'s cap of 85
// caused catastrophic scratch spills: WRITE_SIZE 16->211 MB in round 5).
__global__ __launch_bounds__(512, 4) void attn_kernel(const ushort_t* __restrict__ qk,
                                                      const ushort_t* __restrict__ vT,
                                                      const float* __restrict__ rel,
                                                      const float* __restrict__ res,
                                                      float* __restrict__ out) {
    __shared__ __align__(16) ushort_t slds[2][16][264];   // 528B row stride: 2-way bank alias (free)
    __shared__ float dsums[8][16];
    const int t = threadIdx.x;
    const int w = t >> 6;        // 0..7
    const int l = t & 63;
    const int lr = l & 15;
    const int lg = l >> 4;
    const int b = blockIdx.y;
    const int q0 = blockIdx.x * 16;

    const ushort_t* qkb = qk + (size_t)b * NN * ND;
    const ushort_t* vTb = vT + (size_t)b * ND * NN;
    const float* relb = rel + (size_t)b * NN * NN;

    // hoist Q fragments (A-layout: row = lane&15, k = (lane>>4)*8 + j)
    short8 aq[8];
#pragma unroll
    for (int kb = 0; kb < 8; ++kb)
        aq[kb] = *reinterpret_cast<const short8*>(qkb + (size_t)(q0 + lr) * ND + kb * 32 + lg * 8);

    f32x4 acc0 = (f32x4){0.f, 0.f, 0.f, 0.f};
    f32x4 acc1 = (f32x4){0.f, 0.f, 0.f, 0.f};
    float dsum[4] = {0.f, 0.f, 0.f, 0.f};

    // prefetch rel slice for mt=0
    float rpa[4], rpb[4];
#pragma unroll
    for (int r = 0; r < 4; ++r) {
        const size_t rb = (size_t)(q0 + lg * 4 + r) * NN + w * 32;
        rpa[r] = relb[rb + lr];
        rpb[r] = relb[rb + 16 + lr];
    }

#pragma unroll 2
    for (int mt = 0; mt < 8; ++mt) {
        const int m0 = mt * 256;
        const int mwv = m0 + w * 32;
        const int buf = mt & 1;

        float rp0[4], rp1[4];
#pragma unroll
        for (int r = 0; r < 4; ++r) { rp0[r] = rpa[r]; rp1[r] = rpb[r]; }
        if (mt < 7) {   // prefetch next iter's rel slice (hides HBM latency under this iter)
            const int mn = (mt + 1) * 256 + w * 32;
#pragma unroll
            for (int r = 0; r < 4; ++r) {
                const size_t rb = (size_t)(q0 + lg * 4 + r) * NN + mn;
                rpa[r] = relb[rb + lr];
                rpb[r] = relb[rb + 16 + lr];
            }
        }

        // S[16q][32m] = Q . K^T over K=256
        f32x4 s0 = (f32x4){0.f, 0.f, 0.f, 0.f};
        f32x4 s1 = (f32x4){0.f, 0.f, 0.f, 0.f};
#pragma unroll
        for (int kb = 0; kb < 8; ++kb) {
            short8 b0 = *reinterpret_cast<const short8*>(qkb + (size_t)(mwv + lr) * ND + kb * 32 + lg * 8);
            short8 b1 = *reinterpret_cast<const short8*>(qkb + (size_t)(mwv + 16 + lr) * ND + kb * 32 + lg * 8);
            s0 = __builtin_amdgcn_mfma_f32_16x16x32_bf16(aq[kb], b0, s0, 0, 0, 0);
            s1 = __builtin_amdgcn_mfma_f32_16x16x32_bf16(aq[kb], b1, s1, 0, 0, 0);
        }

        // scale * rel_pos, denom accumulate, stage S (bf16) to LDS
#pragma unroll
        for (int r = 0; r < 4; ++r) {
            float v0 = s0[r] * SCALE * rp0[r];
            float v1 = s1[r] * SCALE * rp1[r];
            dsum[r] += v0 + v1;
            slds[buf][lg * 4 + r][w * 32 + lr] = f2b(v0);
            slds[buf][lg * 4 + r][w * 32 + 16 + lr] = f2b(v1);
        }
        __syncthreads();

        // PV: numer[16q][32d-slice] += S(16x256) . V(256m x 32d)
#pragma unroll
        for (int kt = 0; kt < 8; ++kt) {
            short8 pa = *reinterpret_cast<const short8*>(&slds[buf][lr][kt * 32 + lg * 8]);
            short8 bv0 = *reinterpret_cast<const short8*>(
                vTb + (size_t)(w * 32 + lr) * NN + m0 + kt * 32 + lg * 8);
            short8 bv1 = *reinterpret_cast<const short8*>(
                vTb + (size_t)(w * 32 + 16 + lr) * NN + m0 + kt * 32 + lg * 8);
            acc0 = __builtin_amdgcn_mfma_f32_16x16x32_bf16(pa, bv0, acc0, 0, 0, 0);
            acc1 = __builtin_amdgcn_mfma_f32_16x16x32_bf16(pa, bv1, acc1, 0, 0, 0);
        }
    }

    // denom: reduce over the 16 lanes of each group, then across the 8 waves
#pragma unroll
    for (int r = 0; r < 4; ++r) {
        float v = dsum[r];
        v += __shfl_xor(v, 1, 64);
        v += __shfl_xor(v, 2, 64);
        v += __shfl_xor(v, 4, 64);
        v += __shfl_xor(v, 8, 64);
        dsum[r] = v;
    }
    __syncthreads();   // all slds reads done before dsums reuse of LDS timeline
    if (lr == 0) {
#pragma unroll
        for (int r = 0; r < 4; ++r) dsums[w][lg * 4 + r] = dsum[r];
    }
    __syncthreads();
    float inv[4];
#pragma unroll
    for (int r = 0; r < 4; ++r) {
        const int q = lg * 4 + r;
        float tot = 0.f;
#pragma unroll
        for (int ww = 0; ww < 8; ++ww) tot += dsums[ww][q];
        inv[r] = 1.0f / (tot + 1e-6f);
    }

#pragma unroll
    for (int r = 0; r < 4; ++r) {
        const size_t o = ((size_t)b * NN + q0 + lg * 4 + r) * ND + w * 32 + lr;
        float v0 = acc0[r] * inv[r] + res[o];
        float v1 = acc1[r] * inv[r] + res[o + 16];
        out[o] = fmaxf(v0, 0.f);
        out[o + 16] = fmaxf(v1, 0.f);
    }
}

extern "C" void kernel_launch(void* const* d_in, const int* in_sizes, int n_in,
                              void* d_out, int out_size, void* d_ws, size_t ws_size,
                              hipStream_t stream) {
    const float* x    = (const float*)d_in[0];
    const float* rel  = (const float*)d_in[1];
    const float* Wqkv = (const float*)d_in[2];
    const float* bqkv = (const float*)d_in[3];
    const float* Wd   = (const float*)d_in[4];
    const float* bd   = (const float*)d_in[5];
    float* out = (float*)d_out;

    char* ws = (char*)d_ws;
    ushort_t* Wb  = (ushort_t*)(ws + 0);               // 384 KB
    ushort_t* xg  = (ushort_t*)(ws + 0x80000);         //   8 MB
    ushort_t* qkb = (ushort_t*)(ws + 0x880000);        //   8 MB
    ushort_t* vT  = (ushort_t*)(ws + 0x1080000);       //   8 MB
    float*    res = (float*)(ws + 0x1880000);          //  16 MB

    deggate_kernel<<<NB * NN, 256, 0, stream>>>(rel, x, Wd, bd, xg);
    wconv_kernel<<<(3 * ND * ND) / 1024, 256, 0, stream>>>(Wqkv, Wb);
    qkv_kernel<<<dim3(NB * NN / 64, 12), 256, 0, stream>>>(xg, Wb, bqkv, qkb, vT, res);
    attn_kernel<<<dim3(NN / 16, NB), 512, 0, stream>>>(qkb, vT, rel, res, out);
}